// Round 5
// baseline (1332.674 us; speedup 1.0000x reference)
//
#include <hip/hip_runtime.h>
#include <hip/hip_bf16.h>

#define D 128

typedef float f32x4  __attribute__((ext_vector_type(4)));
typedef __attribute__((ext_vector_type(8))) __bf16 bh8;

__device__ inline float bf2f(unsigned short u) {
    union { unsigned int i; float f; } x; x.i = ((unsigned int)u) << 16; return x.f;
}
__device__ inline unsigned short f2bf(float f) {
    union { float f; unsigned int i; } x; x.f = f;
    return (unsigned short)((x.i + 0x7fffu + ((x.i >> 16) & 1u)) >> 16);
}
__device__ inline void acc2(unsigned int u, float& a, float& b) {
    union { unsigned int i; float f; } lo, hi;
    lo.i = u << 16; hi.i = u & 0xffff0000u;
    a += lo.f; b += hi.f;
}

// ---------------- CSR build ----------------
__global__ void k_hist(const int* __restrict__ edges, int E, int* __restrict__ deg) {
    int e = blockIdx.x * blockDim.x + threadIdx.x;
    if (e < E) {
        atomicAdd(&deg[edges[2 * e]], 1);
        atomicAdd(&deg[edges[2 * e + 1]], 1);
    }
}

__global__ void k_scan1(const int* __restrict__ deg, int n,
                        int* __restrict__ incl, int* __restrict__ bsum) {
    __shared__ int lds[1024];
    int t = threadIdx.x;
    int i = blockIdx.x * 1024 + t;
    int v = (i < n) ? deg[i] : 0;
    int cur = v;
    lds[t] = cur;
    __syncthreads();
    for (int off = 1; off < 1024; off <<= 1) {
        int add = (t >= off) ? lds[t - off] : 0;
        __syncthreads();
        cur += add;
        lds[t] = cur;
        __syncthreads();
    }
    if (i < n) incl[i] = cur;
    if (t == 1023) bsum[blockIdx.x] = cur;
}

__global__ void k_scan2(int* __restrict__ bsum, int nb) {
    __shared__ int lds[128];
    int t = threadIdx.x;
    int v = (t < nb) ? bsum[t] : 0;
    int cur = v;
    lds[t] = cur;
    __syncthreads();
    for (int off = 1; off < 128; off <<= 1) {
        int add = (t >= off) ? lds[t - off] : 0;
        __syncthreads();
        cur += add;
        lds[t] = cur;
        __syncthreads();
    }
    if (t < nb) bsum[t] = cur - v;  // exclusive
}

__global__ void k_scan3(const int* __restrict__ incl, const int* __restrict__ deg,
                        const int* __restrict__ bsum, int n, int twoE,
                        int* __restrict__ rowstart, int* __restrict__ cursor) {
    int i = blockIdx.x * blockDim.x + threadIdx.x;
    if (i < n) {
        int r = incl[i] - deg[i] + bsum[i >> 10];
        rowstart[i] = r;
        cursor[i] = r;
    }
    if (i == 0) rowstart[n] = twoE;
}

__global__ void k_fill(const int* __restrict__ edges, int E,
                       int* __restrict__ cursor, int* __restrict__ adj) {
    int e = blockIdx.x * blockDim.x + threadIdx.x;
    if (e < E) {
        int a = edges[2 * e], b = edges[2 * e + 1];
        adj[atomicAdd(&cursor[a], 1)] = b;
        adj[atomicAdd(&cursor[b], 1)] = a;
    }
}

// ---------------- weight prep: bf16, K-chunked layout ----------------
// wb[l][chunk=kk>>5][o][kk&31], kk = m*128+k (m=0: W0, m=1: W1)
__global__ void k_wprep(const float* __restrict__ W0_1, const float* __restrict__ W1_1,
                        const float* __restrict__ W0_h, const float* __restrict__ W1_h,
                        unsigned short* __restrict__ wb) {
    int idx = blockIdx.x * 256 + threadIdx.x;
    if (idx >= 13 * 2 * 128 * 128) return;
    int k = idx & 127;
    int o = (idx >> 7) & 127;
    int m = (idx >> 14) & 1;
    int l = idx >> 15;
    const float* src = (l == 0) ? (m ? W1_1 : W0_1)
                                : ((m ? W1_h : W0_h) + (size_t)(l - 1) * 16384);
    float v = src[o * 128 + k];
    int kk = m * 128 + k;
    wb[(size_t)l * 32768 + (kk >> 5) * 4096 + o * 32 + (kk & 31)] = f2bf(v);
}

// ---------------- fp32 -> bf16 convert ----------------
__global__ void k_cvt(const float* __restrict__ in, unsigned short* __restrict__ out, int n4) {
    int i = blockIdx.x * blockDim.x + threadIdx.x;
    if (i >= n4) return;
    f32x4 v = *(const f32x4*)&in[(size_t)i * 4];
    unsigned short u[4];
    #pragma unroll
    for (int j = 0; j < 4; ++j) u[j] = f2bf(v[j]);
    *(uint2*)&out[(size_t)i * 4] = *(uint2*)u;
}

// ---------------- bf16 add: c = a + b ----------------
__global__ void k_addb(const unsigned short* __restrict__ a, const unsigned short* __restrict__ b,
                       unsigned short* __restrict__ c, int n2) {
    int i = blockIdx.x * blockDim.x + threadIdx.x;
    if (i >= n2) return;
    unsigned int ua = ((const unsigned int*)a)[i];
    unsigned int ub = ((const unsigned int*)b)[i];
    union { unsigned int i; float f; } la, ha, lb, hb;
    la.i = ua << 16; ha.i = ua & 0xffff0000u;
    lb.i = ub << 16; hb.i = ub & 0xffff0000u;
    unsigned int out = ((unsigned int)f2bf(ha.f + hb.f) << 16) | f2bf(la.f + lb.f);
    ((unsigned int*)c)[i] = out;
}

// ---------------- neighbor aggregation (bf16 in/out, fp32 accum) ----------------
// wave per node; one vector adj load + shfl broadcast => up to 8 row-loads in flight
__global__ __launch_bounds__(256) void k_agg(
    const unsigned short* __restrict__ x, const int* __restrict__ rowstart,
    const int* __restrict__ adj, unsigned short* __restrict__ s, int n) {
    int node = blockIdx.x * 4 + (threadIdx.x >> 6);
    int lane = threadIdx.x & 63;
    if (node >= n) return;
    int r0 = rowstart[node], r1 = rowstart[node + 1];
    float a[8], b[8];
    #pragma unroll
    for (int k = 0; k < 8; ++k) { a[k] = 0.f; b[k] = 0.f; }
    for (int p = r0; p < r1; p += 8) {
        int q = p + (lane & 7);
        int idx = (q < r1) ? adj[q] : 0;
        unsigned int u[8];
        #pragma unroll
        for (int k = 0; k < 8; ++k) {
            int j = __shfl(idx, k);
            u[k] = *(const unsigned int*)&x[(size_t)j * D + lane * 2];
        }
        #pragma unroll
        for (int k = 0; k < 8; ++k)
            if (p + k < r1) acc2(u[k], a[k], b[k]);
    }
    float f0 = ((a[0] + a[1]) + (a[2] + a[3])) + ((a[4] + a[5]) + (a[6] + a[7]));
    float f1 = ((b[0] + b[1]) + (b[2] + b[3])) + ((b[4] + b[5]) + (b[6] + b[7]));
    unsigned int out = ((unsigned int)f2bf(f1) << 16) | f2bf(f0);
    *(unsigned int*)&s[(size_t)node * D + lane * 2] = out;
}

// ---------------- MFMA GEMM: out[i][o] = act([x_i, s_i] @ [W0T;W1T] + b0 + deg*b1) ----------------
// 256 threads = 4 waves; block tile 64 nodes x 128 outs; K=256 in 8 chunks of 32.
// Each wave computes a 32x64 subtile (acc = 8 f32x4 = 32 VGPR -> no spill with prefetch).
#define ASTR 40
#define OSTR 136
__global__ __launch_bounds__(256) void k_gemm(
    const unsigned short* __restrict__ x,   // [n][128] bf16
    const unsigned short* __restrict__ s,   // [n][128] bf16
    const unsigned short* __restrict__ wb,  // layer weights, chunked [8][128][32] bf16
    const float* __restrict__ b0, const float* __restrict__ b1,
    const int* __restrict__ deg,
    unsigned short* __restrict__ out,       // [n][128] bf16
    float* __restrict__ out32,              // optional fp32 copy (aux), may be null
    int n, int do_relu) {
    __shared__ __align__(16) unsigned short LDS[64 * OSTR];  // 17408 B
    unsigned short* Alds = LDS;                // 64*ASTR shorts
    unsigned short* Blds = LDS + 64 * ASTR;    // 128*ASTR shorts (ends at 7680 < 8704)
    int t = threadIdx.x;
    int node0 = blockIdx.x * 64;
    int lane = t & 63;
    int wave = t >> 6;
    int wm = (wave & 1) * 32;
    int wn = (wave >> 1) * 64;
    int mlane = lane & 15;
    int quad = lane >> 4;

    int rowAa = t >> 2;          // 0..63
    int segAa = (t & 3) * 8;

    f32x4 acc[2][4];
    #pragma unroll
    for (int i = 0; i < 2; ++i)
        #pragma unroll
        for (int j = 0; j < 4; ++j) acc[i][j] = (f32x4){0.f, 0.f, 0.f, 0.f};

    uint4 ra, rb[2];
    auto fetch = [&](int kc) {
        const unsigned short* srcA = (kc < 4) ? x : s;
        int kbase = (kc & 3) * 32;
        int g = node0 + rowAa;
        uint4 v = {0u, 0u, 0u, 0u};
        if (g < n) v = *(const uint4*)&srcA[(size_t)g * D + kbase + segAa];
        ra = v;
        #pragma unroll
        for (int p = 0; p < 2; ++p)
            rb[p] = *(const uint4*)&wb[(size_t)kc * 4096 + (size_t)(p * 256 + t) * 8];
    };

    fetch(0);
    for (int kc = 0; kc < 8; ++kc) {
        __syncthreads();   // previous chunk's frag reads complete
        *(uint4*)&Alds[rowAa * ASTR + segAa] = ra;
        #pragma unroll
        for (int p = 0; p < 2; ++p) {
            int c = p * 256 + t;
            *(uint4*)&Blds[(c >> 2) * ASTR + (c & 3) * 8] = rb[p];
        }
        __syncthreads();
        if (kc < 7) fetch(kc + 1);   // overlap next-chunk loads with MFMA below

        bh8 af[2], bf_[4];
        #pragma unroll
        for (int i = 0; i < 2; ++i)
            af[i] = *(const bh8*)&Alds[(wm + i * 16 + mlane) * ASTR + quad * 8];
        #pragma unroll
        for (int j = 0; j < 4; ++j)
            bf_[j] = *(const bh8*)&Blds[(wn + j * 16 + mlane) * ASTR + quad * 8];
        #pragma unroll
        for (int i = 0; i < 2; ++i)
            #pragma unroll
            for (int j = 0; j < 4; ++j)
                acc[i][j] = __builtin_amdgcn_mfma_f32_16x16x32_bf16(af[i], bf_[j], acc[i][j], 0, 0, 0);
    }

    // ---- epilogue: bias + deg*b1 + relu -> LDS transpose -> coalesced stores ----
    __syncthreads();   // done with A/B staging buffers; reuse LDS as Olds
    #pragma unroll
    for (int i = 0; i < 2; ++i) {
        int mrow = wm + i * 16 + quad * 4;
        #pragma unroll
        for (int j = 0; j < 4; ++j) {
            int nn = wn + j * 16 + mlane;
            float b0v = b0[nn], b1v = b1[nn];
            #pragma unroll
            for (int r = 0; r < 4; ++r) {
                int g = node0 + mrow + r;
                float dg = (g < n) ? (float)deg[g] : 0.f;
                float val = acc[i][j][r] + b0v + dg * b1v;
                if (do_relu) val = fmaxf(val, 0.f);
                LDS[(mrow + r) * OSTR + nn] = f2bf(val);
            }
        }
    }
    __syncthreads();
    // bf16 store: 4 passes, 16 lanes x 16B = one full 256B node row per 16 threads
    #pragma unroll
    for (int pass = 0; pass < 4; ++pass) {
        int row = pass * 16 + (t >> 4);
        int seg = (t & 15) * 8;
        int g = node0 + row;
        if (g < n)
            *(uint4*)&out[(size_t)g * D + seg] = *(const uint4*)&LDS[row * OSTR + seg];
    }
    if (out32) {
        #pragma unroll
        for (int pass = 0; pass < 8; ++pass) {
            int row = pass * 8 + (t >> 5);
            int seg = (t & 31) * 4;
            int g = node0 + row;
            if (g < n) {
                f32x4 v;
                #pragma unroll
                for (int j = 0; j < 4; ++j) v[j] = bf2f(LDS[row * OSTR + seg + j]);
                *(f32x4*)&out32[(size_t)g * D + seg] = v;
            }
        }
    }
}

// ---------------- last layer (D_out = 3, fp32 out, no relu) ----------------
__global__ void k_last(const unsigned short* __restrict__ z, const unsigned short* __restrict__ sz,
                       const float* __restrict__ W0, const float* __restrict__ b0,
                       const float* __restrict__ W1, const float* __restrict__ b1,
                       const int* __restrict__ deg, float* __restrict__ vert, int n) {
    int t = threadIdx.x;
    int lane = t & 63;
    int node = blockIdx.x * 4 + (t >> 6);
    if (node >= n) return;
    float z0 = bf2f(z[(size_t)node * D + lane]), z1 = bf2f(z[(size_t)node * D + 64 + lane]);
    float s0 = bf2f(sz[(size_t)node * D + lane]), s1 = bf2f(sz[(size_t)node * D + 64 + lane]);
    float dg = (float)deg[node];
    #pragma unroll
    for (int o = 0; o < 3; ++o) {
        float p = z0 * W0[o * D + lane] + z1 * W0[o * D + 64 + lane]
                + s0 * W1[o * D + lane] + s1 * W1[o * D + 64 + lane];
        for (int off = 32; off > 0; off >>= 1) p += __shfl_down(p, off);
        if (lane == 0) vert[(size_t)node * 3 + o] = p + b0[o] + dg * b1[o];
    }
}

extern "C" void kernel_launch(void* const* d_in, const int* in_sizes, int n_in,
                              void* d_out, int out_size, void* d_ws, size_t ws_size,
                              hipStream_t stream) {
    const float* features = (const float*)d_in[0];
    const int*   edges    = (const int*)d_in[1];
    const float* W0_1 = (const float*)d_in[2];
    const float* b0_1 = (const float*)d_in[3];
    const float* W1_1 = (const float*)d_in[4];
    const float* b1_1 = (const float*)d_in[5];
    const float* W0_h = (const float*)d_in[6];
    const float* b0_h = (const float*)d_in[7];
    const float* W1_h = (const float*)d_in[8];
    const float* b1_h = (const float*)d_in[9];
    const float* W0_l = (const float*)d_in[10];
    const float* b0_l = (const float*)d_in[11];
    const float* W1_l = (const float*)d_in[12];
    const float* b1_l = (const float*)d_in[13];

    const int N_ = 100000, E_ = 300000;
    float* vert = (float*)d_out;                    // N*3
    float* aux  = (float*)d_out + (size_t)N_ * 3;   // N*128 fp32

    char* w = (char*)d_ws;
    auto alloc = [&](size_t bytes) {
        char* p = w;
        w += (bytes + 255) & ~(size_t)255;
        return p;
    };
    unsigned short* wb    = (unsigned short*)alloc((size_t)13 * 32768 * 2);
    unsigned short* xf    = (unsigned short*)alloc((size_t)N_ * D * 2);
    unsigned short* resid = (unsigned short*)alloc((size_t)N_ * D * 2);
    unsigned short* xa    = (unsigned short*)alloc((size_t)N_ * D * 2);
    unsigned short* xb    = (unsigned short*)alloc((size_t)N_ * D * 2);
    unsigned short* sb    = (unsigned short*)alloc((size_t)N_ * D * 2);
    int* deg    = (int*)alloc((size_t)N_ * 4);
    int* incl   = (int*)alloc((size_t)N_ * 4);
    int* rowst  = (int*)alloc((size_t)(N_ + 1) * 4);
    int* cursor = (int*)alloc((size_t)N_ * 4);
    int* bsum   = (int*)alloc(128 * 4);
    int* adj    = (int*)alloc((size_t)2 * E_ * 4);

    // CSR build
    hipMemsetAsync(deg, 0, (size_t)N_ * 4, stream);
    k_hist<<<(E_ + 255) / 256, 256, 0, stream>>>(edges, E_, deg);
    int nb = (N_ + 1023) / 1024;   // 98
    k_scan1<<<nb, 1024, 0, stream>>>(deg, N_, incl, bsum);
    k_scan2<<<1, 128, 0, stream>>>(bsum, nb);
    k_scan3<<<(N_ + 255) / 256, 256, 0, stream>>>(incl, deg, bsum, N_, 2 * E_, rowst, cursor);
    k_fill<<<(E_ + 255) / 256, 256, 0, stream>>>(edges, E_, cursor, adj);

    // weight + feature conversion
    k_wprep<<<(13 * 2 * 16384 + 255) / 256, 256, 0, stream>>>(W0_1, W1_1, W0_h, W1_h, wb);
    k_cvt<<<(N_ * D / 4 + 255) / 256, 256, 0, stream>>>(features, xf, N_ * D / 4);

    int gblocks = (N_ + 63) / 64;    // 1563
    int ablocks = (N_ + 3) / 4;

    // layer 1: xf -> resid
    k_agg<<<ablocks, 256, 0, stream>>>(xf, rowst, adj, sb, N_);
    k_gemm<<<gblocks, 256, 0, stream>>>(xf, sb, wb, b0_1, b1_1, deg, resid, nullptr, N_, 1);

    // 12 hidden layers
    for (int h = 0; h < 12; ++h) {
        const unsigned short* in = (h == 0) ? resid : ((h & 1) ? xa : xb);
        unsigned short* outp = (h & 1) ? xb : xa;
        float* o32 = (h == 11) ? aux : nullptr;
        k_agg<<<ablocks, 256, 0, stream>>>(in, rowst, adj, sb, N_);
        k_gemm<<<gblocks, 256, 0, stream>>>(in, sb, wb + (size_t)(1 + h) * 32768,
                                            b0_h + h * 128, b1_h + h * 128, deg, outp, o32, N_, 1);
    }

    // last layer: z = resid + x12 (in xb); vertices = gconv(z), no relu
    k_addb<<<(N_ * D / 2 + 255) / 256, 256, 0, stream>>>(resid, xb, xa, N_ * D / 2);
    k_agg<<<ablocks, 256, 0, stream>>>(xa, rowst, adj, sb, N_);
    k_last<<<ablocks, 256, 0, stream>>>(xa, sb, W0_l, b0_l, W1_l, b1_l, deg, vert, N_);
}